// Round 1
// baseline (3380.801 us; speedup 1.0000x reference)
//
#include <hip/hip_runtime.h>
#include <math.h>

// Problem dims
#define BB 4
#define LL 1024
#define HID 512
#define NH 8
#define HD 64
#define PROJ 2048
#define NLAYER 2
#define TOK (BB*LL)          // 4096
#define QKV3 (3*NH*HD)       // 1536
#define LN_EPS 1e-5f

// ---------------- reductions ----------------
__device__ inline float wave_sum(float v) {
#pragma unroll
    for (int m = 32; m; m >>= 1) v += __shfl_xor(v, m, 64);
    return v;
}
__device__ inline float wave_max(float v) {
#pragma unroll
    for (int m = 32; m; m >>= 1) v = fmaxf(v, __shfl_xor(v, m, 64));
    return v;
}

// block (256 threads = 4 waves) reduce; red is a 4-float shared scratch.
// Safe to reuse the same scratch back-to-back: write, sync, read, sync.
__device__ inline float block_sum256(float v, float* red) {
    v = wave_sum(v);
    int lane = threadIdx.x & 63, wid = threadIdx.x >> 6;
    if (lane == 0) red[wid] = v;
    __syncthreads();
    float r = red[0] + red[1] + red[2] + red[3];
    __syncthreads();
    return r;
}
__device__ inline float block_max256(float v, float* red) {
    v = wave_max(v);
    int lane = threadIdx.x & 63, wid = threadIdx.x >> 6;
    if (lane == 0) red[wid] = v;
    __syncthreads();
    float r = fmaxf(fmaxf(red[0], red[1]), fmaxf(red[2], red[3]));
    __syncthreads();
    return r;
}

// ---------------- LayerNorm (two-pass, matches reference) ----------------
// one block (256 thr) per row of 512
__global__ __launch_bounds__(256) void ln_kernel(
    const float* __restrict__ x, const float* __restrict__ g,
    const float* __restrict__ b, float* __restrict__ y)
{
    __shared__ float red[4];
    int row = blockIdx.x;
    const float* xr = x + (size_t)row * HID;
    float* yr = y + (size_t)row * HID;
    int t = threadIdx.x;
    float v0 = xr[t], v1 = xr[t + 256];
    float mean = block_sum256(v0 + v1, red) * (1.0f / HID);
    float d0 = v0 - mean, d1 = v1 - mean;
    float var = block_sum256(d0 * d0 + d1 * d1, red) * (1.0f / HID);
    float rstd = rsqrtf(var + LN_EPS);
    yr[t]       = d0 * rstd * g[t]       + b[t];
    yr[t + 256] = d1 * rstd * g[t + 256] + b[t + 256];
}

// ---------------- f32 tiled GEMM: C = A(MxK) @ W(KxN) + bias [,relu][,+resid]
// 64x64 tile, BK=16, 256 threads, 4x4 per thread
__global__ __launch_bounds__(256) void gemm_kernel(
    const float* __restrict__ A, const float* __restrict__ W,
    const float* __restrict__ bias, const float* __restrict__ resid,
    float* __restrict__ C, int M, int N, int K, int relu)
{
    __shared__ float As[64][17];
    __shared__ float Bs[16][65];
    int tid = threadIdx.x;
    int tx = tid & 15, ty = tid >> 4;
    int row0 = blockIdx.y * 64, col0 = blockIdx.x * 64;
    float acc[4][4] = {};
    for (int k0 = 0; k0 < K; k0 += 16) {
        for (int i = tid; i < 64 * 16; i += 256) {
            int r = i >> 4, kk = i & 15;
            As[r][kk] = A[(size_t)(row0 + r) * K + k0 + kk];
        }
        for (int i = tid; i < 16 * 64; i += 256) {
            int kk = i >> 6, c = i & 63;
            Bs[kk][c] = W[(size_t)(k0 + kk) * N + col0 + c];
        }
        __syncthreads();
#pragma unroll
        for (int kk = 0; kk < 16; ++kk) {
            float a[4], bb[4];
#pragma unroll
            for (int i = 0; i < 4; ++i) a[i] = As[ty * 4 + i][kk];
#pragma unroll
            for (int j = 0; j < 4; ++j) bb[j] = Bs[kk][tx * 4 + j];
#pragma unroll
            for (int i = 0; i < 4; ++i)
#pragma unroll
                for (int j = 0; j < 4; ++j)
                    acc[i][j] += a[i] * bb[j];
        }
        __syncthreads();
    }
#pragma unroll
    for (int i = 0; i < 4; ++i) {
        int r = row0 + ty * 4 + i;
#pragma unroll
        for (int j = 0; j < 4; ++j) {
            int c = col0 + tx * 4 + j;
            float v = acc[i][j] + bias[c];
            if (relu) v = fmaxf(v, 0.0f);
            if (resid) v += resid[(size_t)r * N + c];
            C[(size_t)r * N + c] = v;
        }
    }
}

// ---------------- attention: one block per (b, h, q) row ----------------
// qkv layout: [TOK][1536] with q|k|v each 512 (head h at h*64)
__global__ __launch_bounds__(256) void attn_kernel(
    const float* __restrict__ qkv, float* __restrict__ av)
{
    __shared__ float sc[LL];
    __shared__ float qv[HD];
    __shared__ float red[4];
    __shared__ float part[4][HD];
    int gid = blockIdx.x;
    int q = gid & (LL - 1);
    int h = (gid >> 10) & (NH - 1);
    int b = gid >> 13;
    int tid = threadIdx.x;
    const float* base = qkv + (size_t)b * LL * QKV3;
    if (tid < HD) qv[tid] = base[(size_t)q * QKV3 + h * HD + tid] * 0.125f; // 1/sqrt(64)
    __syncthreads();
    int nk = q + 1;                      // causal: keys 0..q
    float lmax = -1e30f;
    for (int k = tid; k < nk; k += 256) {
        const float4* kr = reinterpret_cast<const float4*>(
            base + (size_t)k * QKV3 + HID + h * HD);
        float d = 0.0f;
#pragma unroll
        for (int e = 0; e < HD / 4; ++e) {
            float4 kv = kr[e];
            d += qv[e * 4 + 0] * kv.x + qv[e * 4 + 1] * kv.y +
                 qv[e * 4 + 2] * kv.z + qv[e * 4 + 3] * kv.w;
        }
        sc[k] = d;
        lmax = fmaxf(lmax, d);
    }
    float m = block_max256(lmax, red);
    float lsum = 0.0f;
    for (int k = tid; k < nk; k += 256) {
        float e = expf(sc[k] - m);
        sc[k] = e;
        lsum += e;
    }
    float denom = block_sum256(lsum, red);   // sync inside makes sc[] visible
    float inv = 1.0f / denom;
    int d = tid & 63, chunk = tid >> 6;
    float acc = 0.0f;
    for (int k = chunk; k < nk; k += 4)
        acc += sc[k] * base[(size_t)k * QKV3 + 2 * HID + h * HD + d];
    part[chunk][d] = acc;
    __syncthreads();
    if (tid < HD) {
        float o = (part[0][tid] + part[1][tid] + part[2][tid] + part[3][tid]) * inv;
        av[(size_t)(b * LL + q) * (NH * HD) + h * HD + tid] = o;
    }
}

// ---------------- boundary decision + blend, one wave per token ----------------
__global__ __launch_bounds__(64) void bd_kernel(
    const float* __restrict__ outb, const float* __restrict__ layer_x,
    const float* __restrict__ mm, const float* __restrict__ bd_w,
    const float* __restrict__ bd_b, float* __restrict__ d_out)
{
    int t = blockIdx.x;
    int lane = threadIdx.x;
    const float* orow = outb + (size_t)t * HID;
    float dot = 0.0f;
#pragma unroll
    for (int i = 0; i < 8; ++i) dot += orow[lane + 64 * i] * bd_w[lane + 64 * i];
    dot = wave_sum(dot);
    float mmv = mm[t];
    const float* xrow = layer_x + (size_t)t * HID;
    float* yrow = d_out + (size_t)t * HID;
#pragma unroll
    for (int i = 0; i < 8; ++i) {
        int c = lane + 64 * i;
        yrow[c] = orow[c] * mmv + (1.0f - mmv) * xrow[c];
    }
    if (lane == 0) {
        float z = dot + bd_b[0];
        // sigmoid(z) > 0.5  <=>  z > 0
        d_out[(size_t)TOK * HID + t] = (z > 0.0f) ? 1.0f : 0.0f;
    }
}

extern "C" void kernel_launch(void* const* d_in, const int* in_sizes, int n_in,
                              void* d_out, int out_size, void* d_ws, size_t ws_size,
                              hipStream_t stream) {
    const float* layer_x = (const float*)d_in[0];
    // d_in[1] = full_mask (causal triu(1)) — derived from indices instead
    const float* mm      = (const float*)d_in[2];
    const float* qkv_w   = (const float*)d_in[3];
    const float* qkv_b   = (const float*)d_in[4];
    const float* o_w     = (const float*)d_in[5];
    const float* o_b     = (const float*)d_in[6];
    const float* ln1_g   = (const float*)d_in[7];
    const float* ln1_b   = (const float*)d_in[8];
    const float* ff_w1   = (const float*)d_in[9];
    const float* ff_b1   = (const float*)d_in[10];
    const float* ff_w2   = (const float*)d_in[11];
    const float* ff_b2   = (const float*)d_in[12];
    const float* ln2_g   = (const float*)d_in[13];
    const float* ln2_b   = (const float*)d_in[14];
    const float* bd_w    = (const float*)d_in[15];
    const float* bd_b    = (const float*)d_in[16];

    float* ws = (float*)d_ws;
    float* buf_out = ws;                        // TOK*HID       = 2M floats
    float* buf_h   = ws + (size_t)TOK * HID;    // TOK*HID       = 2M floats (h / av)
    float* buf_big = buf_h + (size_t)TOK * HID; // max(TOK*1536, TOK*PROJ) = 8M floats
    size_t need = ((size_t)TOK * HID * 2 + (size_t)TOK * PROJ) * sizeof(float);
    if (ws_size < need) return;  // fail loudly (validation) rather than corrupt

    // residual stream <- layer_x
    hipMemcpyAsync(buf_out, layer_x, (size_t)TOK * HID * sizeof(float),
                   hipMemcpyDeviceToDevice, stream);

    for (int l = 0; l < NLAYER; ++l) {
        const float* qw  = qkv_w + (size_t)l * HID * QKV3;
        const float* qb  = qkv_b + (size_t)l * QKV3;
        const float* ow  = o_w   + (size_t)l * (NH * HD) * HID;
        const float* ob  = o_b   + (size_t)l * HID;
        const float* w1  = ff_w1 + (size_t)l * HID * PROJ;
        const float* b1  = ff_b1 + (size_t)l * PROJ;
        const float* w2  = ff_w2 + (size_t)l * PROJ * HID;
        const float* b2  = ff_b2 + (size_t)l * HID;

        // h = LN1(out)
        ln_kernel<<<TOK, 256, 0, stream>>>(buf_out, ln1_g + (size_t)l * HID,
                                           ln1_b + (size_t)l * HID, buf_h);
        // qkv = h @ qkv_w + qkv_b
        gemm_kernel<<<dim3(QKV3 / 64, TOK / 64), 256, 0, stream>>>(
            buf_h, qw, qb, nullptr, buf_big, TOK, QKV3, HID, 0);
        // av = softmax(qk^T) v   (into buf_h)
        attn_kernel<<<BB * NH * LL, 256, 0, stream>>>(buf_big, buf_h);
        // out = out + av @ o_w + o_b
        gemm_kernel<<<dim3(HID / 64, TOK / 64), 256, 0, stream>>>(
            buf_h, ow, ob, buf_out, buf_out, TOK, HID, NH * HD, 0);
        // h = LN2(out)
        ln_kernel<<<TOK, 256, 0, stream>>>(buf_out, ln2_g + (size_t)l * HID,
                                           ln2_b + (size_t)l * HID, buf_h);
        // ff = relu(h @ w1 + b1)
        gemm_kernel<<<dim3(PROJ / 64, TOK / 64), 256, 0, stream>>>(
            buf_h, w1, b1, nullptr, buf_big, TOK, PROJ, HID, 1);
        // out = out + ff @ w2 + b2
        gemm_kernel<<<dim3(HID / 64, TOK / 64), 256, 0, stream>>>(
            buf_big, w2, b2, buf_out, buf_out, TOK, HID, PROJ, 0);
    }
    // boundary decision + blend
    bd_kernel<<<TOK, 64, 0, stream>>>(buf_out, layer_x, mm, bd_w, bd_b,
                                      (float*)d_out);
}

// Round 2
// 515.987 us; speedup vs baseline: 6.5521x; 6.5521x over previous
//
#include <hip/hip_runtime.h>
#include <math.h>

#define BB 4
#define LL 1024
#define HID 512
#define NH 8
#define HD 64
#define PROJ 2048
#define NLAYER 2
#define TOK (BB*LL)          // 4096
#define QKV3 (3*NH*HD)       // 1536
#define LN_EPS 1e-5f

typedef unsigned short u16;
typedef unsigned int u32;
typedef __attribute__((ext_vector_type(8))) short short8;
typedef __attribute__((ext_vector_type(4))) float f32x4;

#define MFMA16(a,b,c) __builtin_amdgcn_mfma_f32_16x16x32_bf16(a, b, c, 0, 0, 0)

__device__ inline u16 bf16_rne(float x) {
    u32 u = __float_as_uint(x);
    u32 r = (u + 0x7fffu + ((u >> 16) & 1u)) >> 16;
    return (u16)r;
}
__device__ inline float bf16_to_f(u16 h) {
    return __uint_as_float(((u32)h) << 16);
}

// ---------------- reductions (for bd kernel) ----------------
__device__ inline float wave_sum(float v) {
#pragma unroll
    for (int m = 32; m; m >>= 1) v += __shfl_xor(v, m, 64);
    return v;
}

// ---------------- LayerNorm: f32 in -> bf16x2 (hi,lo) out ----------------
__global__ __launch_bounds__(256) void ln_kernel(
    const float* __restrict__ x, const float* __restrict__ g,
    const float* __restrict__ b, u16* __restrict__ yh, u16* __restrict__ yl)
{
    __shared__ float red[4];
    int row = blockIdx.x;
    const float* xr = x + (size_t)row * HID;
    int t = threadIdx.x;
    int lane = t & 63, wid = t >> 6;
    float v0 = xr[t], v1 = xr[t + 256];
    float s = wave_sum(v0 + v1);
    if (lane == 0) red[wid] = s;
    __syncthreads();
    float mean = (red[0] + red[1] + red[2] + red[3]) * (1.0f / HID);
    __syncthreads();
    float d0 = v0 - mean, d1 = v1 - mean;
    s = wave_sum(d0 * d0 + d1 * d1);
    if (lane == 0) red[wid] = s;
    __syncthreads();
    float var = (red[0] + red[1] + red[2] + red[3]) * (1.0f / HID);
    float rstd = rsqrtf(var + LN_EPS);
    float y0 = d0 * rstd * g[t] + b[t];
    float y1 = d1 * rstd * g[t + 256] + b[t + 256];
    size_t o = (size_t)row * HID;
    u16 h0 = bf16_rne(y0), h1 = bf16_rne(y1);
    yh[o + t] = h0;       yl[o + t] = bf16_rne(y0 - bf16_to_f(h0));
    yh[o + t + 256] = h1; yl[o + t + 256] = bf16_rne(y1 - bf16_to_f(h1));
}

// ---------------- weight prep: W f32 [K][N] -> Wt hi/lo bf16 [N][K] -------
__global__ __launch_bounds__(256) void wprep_kernel(
    const float* __restrict__ W, u16* __restrict__ Th, u16* __restrict__ Tl,
    int K, int N)
{
    __shared__ float tile[32][33];
    int tx = threadIdx.x & 31, ty = threadIdx.x >> 5;  // 32 x 8
    int k0 = blockIdx.y * 32, n0 = blockIdx.x * 32;
#pragma unroll
    for (int r = 0; r < 32; r += 8)
        tile[ty + r][tx] = W[(size_t)(k0 + ty + r) * N + n0 + tx];
    __syncthreads();
#pragma unroll
    for (int r = 0; r < 32; r += 8) {
        float v = tile[tx][ty + r];          // = W[k0+tx][n0+ty+r]
        int n = n0 + ty + r, k = k0 + tx;
        u16 h = bf16_rne(v);
        Th[(size_t)n * K + k] = h;
        Tl[(size_t)n * K + k] = bf16_rne(v - bf16_to_f(h));
    }
}

// ---------------- bf16x2-split MFMA GEMM --------------------------------
// C(MxN) = A(MxK) @ W(KxN) + bias, A given as hi/lo [M][K], W as hi/lo [N][K].
// MODE 0: write bf16 hi only (Ch).  MODE 1: Cf[idx] += result (f32 resid).
// MODE 2: relu then write bf16x2 (Ch, Cl).
template<int MODE>
__global__ __launch_bounds__(256) void gemm_mfma(
    const u16* __restrict__ Ah, const u16* __restrict__ Al,
    const u16* __restrict__ Bh, const u16* __restrict__ Bl,
    const float* __restrict__ bias, float* __restrict__ Cf,
    u16* __restrict__ Ch, u16* __restrict__ Cl,
    int M, int N, int K)
{
    const int LDT = 40;  // padded leading dim (ushorts): 80B rows break bank alias
    __shared__ u16 Ash[128 * 40];
    __shared__ u16 Asl[128 * 40];
    __shared__ u16 Bsh[128 * 40];
    __shared__ u16 Bsl[128 * 40];
    int tid = threadIdx.x;
    int row0 = blockIdx.y * 128, col0 = blockIdx.x * 128;
    int w = tid >> 6, lane = tid & 63, hi = lane >> 4, lo16 = lane & 15;
    int wr = w >> 1, wc = w & 1;
    int srow = tid >> 1, shalf = tid & 1;

    f32x4 acc[4][4] = {};

    for (int k0 = 0; k0 < K; k0 += 32) {
        size_t ga = (size_t)(row0 + srow) * K + k0 + shalf * 16;
        size_t gb = (size_t)(col0 + srow) * K + k0 + shalf * 16;
        uint4 a0 = *(const uint4*)(Ah + ga);
        uint4 a1 = *(const uint4*)(Ah + ga + 8);
        uint4 la0 = *(const uint4*)(Al + ga);
        uint4 la1 = *(const uint4*)(Al + ga + 8);
        uint4 b0 = *(const uint4*)(Bh + gb);
        uint4 b1 = *(const uint4*)(Bh + gb + 8);
        uint4 lb0 = *(const uint4*)(Bl + gb);
        uint4 lb1 = *(const uint4*)(Bl + gb + 8);
        __syncthreads();   // previous iter's reads done before overwrite
        int so = srow * LDT + shalf * 16;
        *(uint4*)&Ash[so] = a0;  *(uint4*)&Ash[so + 8] = a1;
        *(uint4*)&Asl[so] = la0; *(uint4*)&Asl[so + 8] = la1;
        *(uint4*)&Bsh[so] = b0;  *(uint4*)&Bsh[so + 8] = b1;
        *(uint4*)&Bsl[so] = lb0; *(uint4*)&Bsl[so + 8] = lb1;
        __syncthreads();

        short8 afh[4], afl[4], bfh[4], bfl[4];
#pragma unroll
        for (int m = 0; m < 4; ++m) {
            int r = (wr * 64 + m * 16 + lo16) * LDT + hi * 8;
            afh[m] = *(const short8*)&Ash[r];
            afl[m] = *(const short8*)&Asl[r];
        }
#pragma unroll
        for (int n = 0; n < 4; ++n) {
            int c = (wc * 64 + n * 16 + lo16) * LDT + hi * 8;
            bfh[n] = *(const short8*)&Bsh[c];
            bfl[n] = *(const short8*)&Bsl[c];
        }
#pragma unroll
        for (int m = 0; m < 4; ++m)
#pragma unroll
            for (int n = 0; n < 4; ++n) {
                acc[m][n] = MFMA16(afh[m], bfh[n], acc[m][n]);
                acc[m][n] = MFMA16(afh[m], bfl[n], acc[m][n]);
                acc[m][n] = MFMA16(afl[m], bfh[n], acc[m][n]);
            }
    }

#pragma unroll
    for (int n = 0; n < 4; ++n) {
        int c = col0 + wc * 64 + n * 16 + lo16;
        float bv = bias[c];
#pragma unroll
        for (int m = 0; m < 4; ++m) {
            int rbase = row0 + wr * 64 + m * 16 + hi * 4;
#pragma unroll
            for (int r = 0; r < 4; ++r) {
                float x = acc[m][n][r] + bv;
                size_t idx = (size_t)(rbase + r) * N + c;
                if (MODE == 0) {
                    Ch[idx] = bf16_rne(x);
                } else if (MODE == 1) {
                    Cf[idx] += x;
                } else {
                    x = fmaxf(x, 0.0f);
                    u16 hh = bf16_rne(x);
                    Ch[idx] = hh;
                    Cl[idx] = bf16_rne(x - bf16_to_f(hh));
                }
            }
        }
    }
}

// ---------------- flash attention, MFMA bf16 ----------------------------
// qkv: bf16 [TOK][1536] (q|k|v, head h at h*64). out: av hi/lo [TOK][512].
// Block: 256 thr = 4 waves; wave w owns q rows qt*64 + w*16 .. +16.
__global__ __launch_bounds__(256) void attn_mfma(
    const u16* __restrict__ qkv, u16* __restrict__ avh, u16* __restrict__ avl)
{
    __shared__ u16 Ks[64 * 64];   // [k_tok][d], XOR-swizzled rows
    __shared__ u16 Vt[64 * 64];   // [d][k_tok], XOR-swizzled rows
    __shared__ u16 Pl[4 * 1024];  // per-wave [16 q][64 k], XOR-swizzled

    int gid = blockIdx.x;
    int qt = gid & 15;
    int bh = gid >> 4;
    int bb = bh >> 3, h = bh & 7;
    int tid = threadIdx.x;
    int w = tid >> 6, lane = tid & 63, hi = lane >> 4, lo16 = lane & 15;

    // Q fragments (held in regs for the whole block)
    int qtok = bb * LL + qt * 64 + w * 16 + lo16;
    const u16* qsrc = qkv + (size_t)qtok * QKV3 + h * HD;
    short8 qf0 = *(const short8*)(qsrc + hi * 8);
    short8 qf1 = *(const short8*)(qsrc + 32 + hi * 8);

    f32x4 o[4] = {};
    float m_[4] = {-1e30f, -1e30f, -1e30f, -1e30f};
    float l_[4] = {0.f, 0.f, 0.f, 0.f};

    int stok = tid >> 2;          // staging token 0..63
    int spart = tid & 3;

    for (int kt = 0; kt <= qt; ++kt) {
        __syncthreads();  // previous tile fully consumed
        // ---- stage K tile: rows [tok][d 0..63]
        {
            const u16* src = qkv + (size_t)(bb * LL + kt * 64 + stok) * QKV3 + HID + h * HD;
            int p0 = spart * 2;
#pragma unroll
            for (int pp = p0; pp < p0 + 2; ++pp) {
                uint4 v = *(const uint4*)(src + pp * 8);
                u32 dst = (u32)(stok * 128 + pp * 16) ^ ((stok & 7) << 4);
                *(uint4*)((char*)Ks + dst) = v;
            }
        }
        // ---- stage V tile transposed: Vt[d][tok]
        {
            const u16* src = qkv + (size_t)(bb * LL + kt * 64 + stok) * QKV3 + 2 * HID + h * HD;
            union { uint4 v; u16 s[8]; } x0, x1;
            x0.v = *(const uint4*)(src + spart * 16);
            x1.v = *(const uint4*)(src + spart * 16 + 8);
#pragma unroll
            for (int j = 0; j < 8; ++j) {
                int d = spart * 16 + j;
                u32 dst = (u32)(d * 128 + stok * 2) ^ ((d & 7) << 4);
                *(u16*)((char*)Vt + dst) = x0.s[j];
            }
#pragma unroll
            for (int j = 0; j < 8; ++j) {
                int d = spart * 16 + 8 + j;
                u32 dst = (u32)(d * 128 + stok * 2) ^ ((d & 7) << 4);
                *(u16*)((char*)Vt + dst) = x1.s[j];
            }
        }
        __syncthreads();

        // ---- QK^T: s[n][r], q = hi*4+r (local), k = n*16+lo16 (local)
        f32x4 s[4];
#pragma unroll
        for (int n = 0; n < 4; ++n) {
            int tl = n * 16 + lo16;
            u32 off0 = (u32)(tl * 128 + hi * 16) ^ ((tl & 7) << 4);
            u32 off1 = (u32)(tl * 128 + 64 + hi * 16) ^ ((tl & 7) << 4);
            short8 kf0 = *(const short8*)((char*)Ks + off0);
            short8 kf1 = *(const short8*)((char*)Ks + off1);
            f32x4 z = {};
            z = MFMA16(qf0, kf0, z);
            z = MFMA16(qf1, kf1, z);
#pragma unroll
            for (int r = 0; r < 4; ++r) z[r] *= 0.125f;   // 1/sqrt(64)
            s[n] = z;
        }
        // causal mask on the diagonal tile
        if (kt == qt) {
#pragma unroll
            for (int n = 0; n < 4; ++n) {
                int kl = n * 16 + lo16;
#pragma unroll
                for (int r = 0; r < 4; ++r) {
                    int ql = w * 16 + hi * 4 + r;
                    if (kl > ql) s[n][r] = -1e30f;
                }
            }
        }
        // ---- online softmax (per r; k spans 4 frags x 16 lanes of same hi-group)
        float mt[4];
#pragma unroll
        for (int r = 0; r < 4; ++r)
            mt[r] = fmaxf(fmaxf(s[0][r], s[1][r]), fmaxf(s[2][r], s[3][r]));
#pragma unroll
        for (int st = 1; st < 16; st <<= 1)
#pragma unroll
            for (int r = 0; r < 4; ++r)
                mt[r] = fmaxf(mt[r], __shfl_xor(mt[r], st, 64));
        float ps[4];
#pragma unroll
        for (int r = 0; r < 4; ++r) {
            float mn = fmaxf(m_[r], mt[r]);
            float f = __expf(m_[r] - mn);
            l_[r] *= f;
#pragma unroll
            for (int n = 0; n < 4; ++n) o[n][r] *= f;
            m_[r] = mn;
            ps[r] = 0.f;
        }
#pragma unroll
        for (int n = 0; n < 4; ++n)
#pragma unroll
            for (int r = 0; r < 4; ++r) {
                float p = __expf(s[n][r] - m_[r]);
                s[n][r] = p;
                ps[r] += p;
            }
#pragma unroll
        for (int st = 1; st < 16; st <<= 1)
#pragma unroll
            for (int r = 0; r < 4; ++r)
                ps[r] += __shfl_xor(ps[r], st, 64);
#pragma unroll
        for (int r = 0; r < 4; ++r) l_[r] += ps[r];

        // ---- P -> LDS (bf16), per-wave private region
#pragma unroll
        for (int n = 0; n < 4; ++n) {
            int kl = n * 16 + lo16;
#pragma unroll
            for (int r = 0; r < 4; ++r) {
                int ql = hi * 4 + r;
                u32 off = (u32)(w * 2048) + (((u32)(ql * 128 + kl * 2)) ^ ((ql & 7) << 4));
                *(u16*)((char*)Pl + off) = bf16_rne(s[n][r]);
            }
        }
        // ---- PV: O[q][d] += P[q][k] V[k][d]
        short8 pa[2];
#pragma unroll
        for (int c = 0; c < 2; ++c) {
            u32 off = (u32)(w * 2048) + (((u32)(lo16 * 128 + c * 64 + hi * 16)) ^ ((lo16 & 7) << 4));
            pa[c] = *(const short8*)((char*)Pl + off);
        }
#pragma unroll
        for (int n = 0; n < 4; ++n) {
            int dl = n * 16 + lo16;
            u32 ov0 = (u32)(dl * 128 + hi * 16) ^ ((dl & 7) << 4);
            u32 ov1 = (u32)(dl * 128 + 64 + hi * 16) ^ ((dl & 7) << 4);
            short8 vb0 = *(const short8*)((char*)Vt + ov0);
            short8 vb1 = *(const short8*)((char*)Vt + ov1);
            o[n] = MFMA16(pa[0], vb0, o[n]);
            o[n] = MFMA16(pa[1], vb1, o[n]);
        }
    }

    // ---- epilogue: O /= l, write bf16x2
#pragma unroll
    for (int r = 0; r < 4; ++r) {
        float inv = 1.0f / l_[r];
        int tokg = bb * LL + qt * 64 + w * 16 + hi * 4 + r;
#pragma unroll
        for (int n = 0; n < 4; ++n) {
            int d = n * 16 + lo16;
            float v = o[n][r] * inv;
            u16 hh = bf16_rne(v);
            size_t idx = (size_t)tokg * (NH * HD) + h * HD + d;
            avh[idx] = hh;
            avl[idx] = bf16_rne(v - bf16_to_f(hh));
        }
    }
}

// ---------------- boundary decision + blend -----------------------------
__global__ __launch_bounds__(64) void bd_kernel(
    const float* __restrict__ outb, const float* __restrict__ layer_x,
    const float* __restrict__ mm, const float* __restrict__ bd_w,
    const float* __restrict__ bd_b, float* __restrict__ d_out)
{
    int t = blockIdx.x;
    int lane = threadIdx.x;
    const float* orow = outb + (size_t)t * HID;
    float dot = 0.0f;
#pragma unroll
    for (int i = 0; i < 8; ++i) dot += orow[lane + 64 * i] * bd_w[lane + 64 * i];
    dot = wave_sum(dot);
    float mmv = mm[t];
    const float* xrow = layer_x + (size_t)t * HID;
    float* yrow = d_out + (size_t)t * HID;
#pragma unroll
    for (int i = 0; i < 8; ++i) {
        int c = lane + 64 * i;
        yrow[c] = orow[c] * mmv + (1.0f - mmv) * xrow[c];
    }
    if (lane == 0) {
        float z = dot + bd_b[0];
        d_out[(size_t)TOK * HID + t] = (z > 0.0f) ? 1.0f : 0.0f;
    }
}

extern "C" void kernel_launch(void* const* d_in, const int* in_sizes, int n_in,
                              void* d_out, int out_size, void* d_ws, size_t ws_size,
                              hipStream_t stream) {
    const float* layer_x = (const float*)d_in[0];
    const float* mm      = (const float*)d_in[2];
    const float* qkv_w   = (const float*)d_in[3];
    const float* qkv_b   = (const float*)d_in[4];
    const float* o_w     = (const float*)d_in[5];
    const float* o_b     = (const float*)d_in[6];
    const float* ln1_g   = (const float*)d_in[7];
    const float* ln1_b   = (const float*)d_in[8];
    const float* ff_w1   = (const float*)d_in[9];
    const float* ff_b1   = (const float*)d_in[10];
    const float* ff_w2   = (const float*)d_in[11];
    const float* ff_b2   = (const float*)d_in[12];
    const float* ln2_g   = (const float*)d_in[13];
    const float* ln2_b   = (const float*)d_in[14];
    const float* bd_w    = (const float*)d_in[15];
    const float* bd_b    = (const float*)d_in[16];

    char* base = (char*)d_ws;
    float* buf_out = (float*)base;                       //  8388608 B
    u16* h_hi  = (u16*)(base + 8388608);                 //  4194304
    u16* h_lo  = (u16*)(base + 12582912);                //  4194304
    u16* av_hi = (u16*)(base + 16777216);                //  4194304
    u16* av_lo = (u16*)(base + 20971520);                //  4194304
    u16* qkvb  = (u16*)(base + 25165824);                // 12582912 (aliases t)
    u16* t_hi  = (u16*)(base + 25165824);                // 16777216
    u16* t_lo  = (u16*)(base + 41943040);                // 16777216
    u16* wt_hi = (u16*)(base + 58720256);                // 12582912
    u16* wt_lo = (u16*)(base + 71303168);                // 12582912
    size_t need = 83886080;
    if (ws_size < need) return;

    const size_t WST = 3145728;  // per-layer stride in wt region (elems)
    const size_t OFF_QKV = 0, OFF_O = 786432, OFF_FF1 = 1048576, OFF_FF2 = 2097152;

    // weight prep (transpose + bf16x2 split)
    for (int l = 0; l < NLAYER; ++l) {
        size_t wb = (size_t)l * WST;
        wprep_kernel<<<dim3(QKV3 / 32, HID / 32), 256, 0, stream>>>(
            qkv_w + (size_t)l * HID * QKV3, wt_hi + wb + OFF_QKV, wt_lo + wb + OFF_QKV, HID, QKV3);
        wprep_kernel<<<dim3(HID / 32, HID / 32), 256, 0, stream>>>(
            o_w + (size_t)l * HID * HID, wt_hi + wb + OFF_O, wt_lo + wb + OFF_O, HID, HID);
        wprep_kernel<<<dim3(PROJ / 32, HID / 32), 256, 0, stream>>>(
            ff_w1 + (size_t)l * HID * PROJ, wt_hi + wb + OFF_FF1, wt_lo + wb + OFF_FF1, HID, PROJ);
        wprep_kernel<<<dim3(HID / 32, PROJ / 32), 256, 0, stream>>>(
            ff_w2 + (size_t)l * PROJ * HID, wt_hi + wb + OFF_FF2, wt_lo + wb + OFF_FF2, PROJ, HID);
    }

    hipMemcpyAsync(buf_out, layer_x, (size_t)TOK * HID * sizeof(float),
                   hipMemcpyDeviceToDevice, stream);

    for (int l = 0; l < NLAYER; ++l) {
        size_t wb = (size_t)l * WST;
        // h = LN1(out) -> bf16x2
        ln_kernel<<<TOK, 256, 0, stream>>>(buf_out, ln1_g + (size_t)l * HID,
                                           ln1_b + (size_t)l * HID, h_hi, h_lo);
        // qkv = h @ qkv_w + qkv_b  -> bf16
        gemm_mfma<0><<<dim3(QKV3 / 128, TOK / 128), 256, 0, stream>>>(
            h_hi, h_lo, wt_hi + wb + OFF_QKV, wt_lo + wb + OFF_QKV,
            qkv_b + (size_t)l * QKV3, nullptr, qkvb, nullptr, TOK, QKV3, HID);
        // av = softmax(q k^T / 8) v  -> bf16x2
        attn_mfma<<<BB * NH * (LL / 64), 256, 0, stream>>>(qkvb, av_hi, av_lo);
        // out += av @ o_w + o_b
        gemm_mfma<1><<<dim3(HID / 128, TOK / 128), 256, 0, stream>>>(
            av_hi, av_lo, wt_hi + wb + OFF_O, wt_lo + wb + OFF_O,
            o_b + (size_t)l * HID, buf_out, nullptr, nullptr, TOK, HID, NH * HD);
        // h = LN2(out) -> bf16x2
        ln_kernel<<<TOK, 256, 0, stream>>>(buf_out, ln2_g + (size_t)l * HID,
                                           ln2_b + (size_t)l * HID, h_hi, h_lo);
        // t = relu(h @ w1 + b1) -> bf16x2
        gemm_mfma<2><<<dim3(PROJ / 128, TOK / 128), 256, 0, stream>>>(
            h_hi, h_lo, wt_hi + wb + OFF_FF1, wt_lo + wb + OFF_FF1,
            ff_b1 + (size_t)l * PROJ, nullptr, t_hi, t_lo, TOK, PROJ, HID);
        // out += t @ w2 + b2
        gemm_mfma<1><<<dim3(HID / 128, TOK / 128), 256, 0, stream>>>(
            t_hi, t_lo, wt_hi + wb + OFF_FF2, wt_lo + wb + OFF_FF2,
            ff_b2 + (size_t)l * HID, buf_out, nullptr, nullptr, TOK, HID, PROJ);
    }

    bd_kernel<<<TOK, 64, 0, stream>>>(buf_out, layer_x, mm, bd_w, bd_b,
                                      (float*)d_out);
}

// Round 3
// 408.461 us; speedup vs baseline: 8.2769x; 1.2632x over previous
//
#include <hip/hip_runtime.h>
#include <math.h>

#define BB 4
#define LL 1024
#define HID 512
#define NH 8
#define HD 64
#define PROJ 2048
#define NLAYER 2
#define TOK (BB*LL)          // 4096
#define QKV3 (3*NH*HD)       // 1536
#define LN_EPS 1e-5f

typedef unsigned short u16;
typedef unsigned int u32;
typedef __attribute__((ext_vector_type(8))) short short8;
typedef __attribute__((ext_vector_type(4))) float f32x4;

#define MFMA16(a,b,c) __builtin_amdgcn_mfma_f32_16x16x32_bf16(a, b, c, 0, 0, 0)

__device__ inline u16 bf16_rne(float x) {
    u32 u = __float_as_uint(x);
    u32 r = (u + 0x7fffu + ((u >> 16) & 1u)) >> 16;
    return (u16)r;
}
__device__ inline float bf16_to_f(u16 h) {
    return __uint_as_float(((u32)h) << 16);
}

// async global -> LDS, 16B per lane (lds dest wave-uniform base + lane*16)
__device__ __forceinline__ void gl16(const u16* g, u16* l) {
    __builtin_amdgcn_global_load_lds(
        (const __attribute__((address_space(1))) unsigned int*)(g),
        (__attribute__((address_space(3))) unsigned int*)(l),
        16, 0, 0);
}

// ---------------- reductions ----------------
__device__ inline float wave_sum(float v) {
#pragma unroll
    for (int m = 32; m; m >>= 1) v += __shfl_xor(v, m, 64);
    return v;
}

// ---------------- LayerNorm: f32 in -> bf16x2 (hi,lo) out ----------------
__global__ __launch_bounds__(256) void ln_kernel(
    const float* __restrict__ x, const float* __restrict__ g,
    const float* __restrict__ b, u16* __restrict__ yh, u16* __restrict__ yl)
{
    __shared__ float red[4];
    int row = blockIdx.x;
    const float* xr = x + (size_t)row * HID;
    int t = threadIdx.x;
    int lane = t & 63, wid = t >> 6;
    float v0 = xr[t], v1 = xr[t + 256];
    float s = wave_sum(v0 + v1);
    if (lane == 0) red[wid] = s;
    __syncthreads();
    float mean = (red[0] + red[1] + red[2] + red[3]) * (1.0f / HID);
    __syncthreads();
    float d0 = v0 - mean, d1 = v1 - mean;
    s = wave_sum(d0 * d0 + d1 * d1);
    if (lane == 0) red[wid] = s;
    __syncthreads();
    float var = (red[0] + red[1] + red[2] + red[3]) * (1.0f / HID);
    float rstd = rsqrtf(var + LN_EPS);
    float y0 = d0 * rstd * g[t] + b[t];
    float y1 = d1 * rstd * g[t + 256] + b[t + 256];
    size_t o = (size_t)row * HID;
    u16 h0 = bf16_rne(y0), h1 = bf16_rne(y1);
    yh[o + t] = h0;       yl[o + t] = bf16_rne(y0 - bf16_to_f(h0));
    yh[o + t + 256] = h1; yl[o + t + 256] = bf16_rne(y1 - bf16_to_f(h1));
}

// ---------------- weight prep: W f32 [K][N] -> Wt hi/lo bf16 [N][K] -------
__global__ __launch_bounds__(256) void wprep_kernel(
    const float* __restrict__ W, u16* __restrict__ Th, u16* __restrict__ Tl,
    int K, int N)
{
    __shared__ float tile[32][33];
    int tx = threadIdx.x & 31, ty = threadIdx.x >> 5;  // 32 x 8
    int k0 = blockIdx.y * 32, n0 = blockIdx.x * 32;
#pragma unroll
    for (int r = 0; r < 32; r += 8)
        tile[ty + r][tx] = W[(size_t)(k0 + ty + r) * N + n0 + tx];
    __syncthreads();
#pragma unroll
    for (int r = 0; r < 32; r += 8) {
        float v = tile[tx][ty + r];          // = W[k0+tx][n0+ty+r]
        int n = n0 + ty + r, k = k0 + tx;
        u16 h = bf16_rne(v);
        Th[(size_t)n * K + k] = h;
        Tl[(size_t)n * K + k] = bf16_rne(v - bf16_to_f(h));
    }
}

// ---------------- bf16x2-split MFMA GEMM, m97 structure ------------------
// C(MxN) = A(MxK) @ W(KxN) + bias. A hi/lo [M][K], W hi/lo [N][K].
// BM=BN=128, BK=64, 256 thr (4 waves, 2x2 of 64x64).
// LDS: 4 linear arrays [128][64] u16 (Ash,Asl,Bsh,Bsl), global_load_lds w16.
// MODE 0: Ch = bf16(x).  MODE 1: atomicAdd(Cf, x) [split-K via grid.z].
// MODE 2: relu, Ch/Cl bf16x2.
template<int MODE, int SK>
__global__ __launch_bounds__(256) void gemm3(
    const u16* __restrict__ Ah, const u16* __restrict__ Al,
    const u16* __restrict__ Bh, const u16* __restrict__ Bl,
    const float* __restrict__ bias, float* __restrict__ Cf,
    u16* __restrict__ Ch, u16* __restrict__ Cl,
    int M, int N, int K)
{
    __shared__ u16 sm[4 * 128 * 64];     // 64 KB
    int tid = threadIdx.x;
    int w = tid >> 6, lane = tid & 63;
    int hi = lane >> 4, lo16 = lane & 15;
    int wr = w >> 1, wc = w & 1;
    int row0 = blockIdx.y * 128, col0 = blockIdx.x * 128;
    int kchunk = K / SK;
    int kbeg = blockIdx.z * kchunk, kend = kbeg + kchunk;

    const u16* srcs[4] = {Ah, Al, Bh, Bl};
    const int t0s[4] = {row0, row0, col0, col0};
    int rl = lane >> 3;            // row within an 8-row (1 KB) chunk
    int kp = (lane & 7) * 8;       // u16 offset within the 128B row

    f32x4 acc[4][4] = {};

    for (int k0 = kbeg; k0 < kend; k0 += 64) {
        __syncthreads();   // all waves done reading the previous tile
#pragma unroll
        for (int arr = 0; arr < 4; ++arr) {
            const u16* src = srcs[arr];
            int t0 = t0s[arr];
#pragma unroll
            for (int c = 0; c < 4; ++c) {
                int r = w * 32 + c * 8;
                gl16(src + (size_t)(t0 + r + rl) * K + k0 + kp,
                     sm + arr * 8192 + r * 64);
            }
        }
        __syncthreads();   // vmcnt(0) drain: tile resident

#pragma unroll
        for (int ks = 0; ks < 2; ++ks) {
            short8 afh[4], afl[4], bfh[4], bfl[4];
#pragma unroll
            for (int m = 0; m < 4; ++m) {
                int off = (wr * 64 + m * 16 + lo16) * 64 + ks * 32 + hi * 8;
                afh[m] = *(const short8*)&sm[off];           // Ash
                afl[m] = *(const short8*)&sm[8192 + off];    // Asl
            }
#pragma unroll
            for (int n = 0; n < 4; ++n) {
                int off = (wc * 64 + n * 16 + lo16) * 64 + ks * 32 + hi * 8;
                bfh[n] = *(const short8*)&sm[16384 + off];   // Bsh
                bfl[n] = *(const short8*)&sm[24576 + off];   // Bsl
            }
#pragma unroll
            for (int m = 0; m < 4; ++m)
#pragma unroll
                for (int n = 0; n < 4; ++n) {
                    acc[m][n] = MFMA16(afh[m], bfh[n], acc[m][n]);
                    acc[m][n] = MFMA16(afh[m], bfl[n], acc[m][n]);
                    acc[m][n] = MFMA16(afl[m], bfh[n], acc[m][n]);
                }
        }
    }

#pragma unroll
    for (int n = 0; n < 4; ++n) {
        int c = col0 + wc * 64 + n * 16 + lo16;
        float bv = (SK == 1 || blockIdx.z == 0) ? bias[c] : 0.0f;
#pragma unroll
        for (int m = 0; m < 4; ++m) {
            int rbase = row0 + wr * 64 + m * 16 + hi * 4;
#pragma unroll
            for (int r = 0; r < 4; ++r) {
                float x = acc[m][n][r] + bv;
                size_t idx = (size_t)(rbase + r) * N + c;
                if (MODE == 0) {
                    Ch[idx] = bf16_rne(x);
                } else if (MODE == 1) {
                    unsafeAtomicAdd(&Cf[idx], x);
                } else {
                    x = fmaxf(x, 0.0f);
                    u16 hh = bf16_rne(x);
                    Ch[idx] = hh;
                    Cl[idx] = bf16_rne(x - bf16_to_f(hh));
                }
            }
        }
    }
}

// ---------------- flash attention, MFMA bf16 ----------------------------
// qkv: bf16 [TOK][1536] (q|k|v, head h at h*64). out: av hi/lo [TOK][512].
// Block: 256 thr = 4 waves; wave w owns q rows qt*64 + w*16 .. +16.
__global__ __launch_bounds__(256) void attn_mfma(
    const u16* __restrict__ qkv, u16* __restrict__ avh, u16* __restrict__ avl)
{
    __shared__ u16 Ks[64 * 64];   // [k_tok][d], XOR-swizzled rows
    __shared__ u16 Vt[64 * 64];   // [d][k_tok], XOR-swizzled rows
    __shared__ u16 Pl[4 * 1024];  // per-wave [16 q][64 k], XOR-swizzled

    int gid = blockIdx.x;
    int qt = gid & 15;
    int bh = gid >> 4;
    int bb = bh >> 3, h = bh & 7;
    int tid = threadIdx.x;
    int w = tid >> 6, lane = tid & 63, hi = lane >> 4, lo16 = lane & 15;

    // Q fragments (held in regs for the whole block)
    int qtok = bb * LL + qt * 64 + w * 16 + lo16;
    const u16* qsrc = qkv + (size_t)qtok * QKV3 + h * HD;
    short8 qf0 = *(const short8*)(qsrc + hi * 8);
    short8 qf1 = *(const short8*)(qsrc + 32 + hi * 8);

    f32x4 o[4] = {};
    float m_[4] = {-1e30f, -1e30f, -1e30f, -1e30f};
    float l_[4] = {0.f, 0.f, 0.f, 0.f};

    int stok = tid >> 2;          // staging token 0..63
    int spart = tid & 3;

    for (int kt = 0; kt <= qt; ++kt) {
        __syncthreads();  // previous tile fully consumed
        // ---- stage K tile: rows [tok][d 0..63]
        {
            const u16* src = qkv + (size_t)(bb * LL + kt * 64 + stok) * QKV3 + HID + h * HD;
            int p0 = spart * 2;
#pragma unroll
            for (int pp = p0; pp < p0 + 2; ++pp) {
                uint4 v = *(const uint4*)(src + pp * 8);
                u32 dst = (u32)(stok * 128 + pp * 16) ^ ((stok & 7) << 4);
                *(uint4*)((char*)Ks + dst) = v;
            }
        }
        // ---- stage V tile transposed: Vt[d][tok]
        {
            const u16* src = qkv + (size_t)(bb * LL + kt * 64 + stok) * QKV3 + 2 * HID + h * HD;
            union { uint4 v; u16 s[8]; } x0, x1;
            x0.v = *(const uint4*)(src + spart * 16);
            x1.v = *(const uint4*)(src + spart * 16 + 8);
#pragma unroll
            for (int j = 0; j < 8; ++j) {
                int d = spart * 16 + j;
                u32 dst = (u32)(d * 128 + stok * 2) ^ ((d & 7) << 4);
                *(u16*)((char*)Vt + dst) = x0.s[j];
            }
#pragma unroll
            for (int j = 0; j < 8; ++j) {
                int d = spart * 16 + 8 + j;
                u32 dst = (u32)(d * 128 + stok * 2) ^ ((d & 7) << 4);
                *(u16*)((char*)Vt + dst) = x1.s[j];
            }
        }
        __syncthreads();

        // ---- QK^T: s[n][r], q = hi*4+r (local), k = n*16+lo16 (local)
        f32x4 s[4];
#pragma unroll
        for (int n = 0; n < 4; ++n) {
            int tl = n * 16 + lo16;
            u32 off0 = (u32)(tl * 128 + hi * 16) ^ ((tl & 7) << 4);
            u32 off1 = (u32)(tl * 128 + 64 + hi * 16) ^ ((tl & 7) << 4);
            short8 kf0 = *(const short8*)((char*)Ks + off0);
            short8 kf1 = *(const short8*)((char*)Ks + off1);
            f32x4 z = {};
            z = MFMA16(qf0, kf0, z);
            z = MFMA16(qf1, kf1, z);
#pragma unroll
            for (int r = 0; r < 4; ++r) z[r] *= 0.125f;   // 1/sqrt(64)
            s[n] = z;
        }
        // causal mask on the diagonal tile
        if (kt == qt) {
#pragma unroll
            for (int n = 0; n < 4; ++n) {
                int kl = n * 16 + lo16;
#pragma unroll
                for (int r = 0; r < 4; ++r) {
                    int ql = w * 16 + hi * 4 + r;
                    if (kl > ql) s[n][r] = -1e30f;
                }
            }
        }
        // ---- online softmax (per r; k spans 4 frags x 16 lanes of same hi-group)
        float mt[4];
#pragma unroll
        for (int r = 0; r < 4; ++r)
            mt[r] = fmaxf(fmaxf(s[0][r], s[1][r]), fmaxf(s[2][r], s[3][r]));
#pragma unroll
        for (int st = 1; st < 16; st <<= 1)
#pragma unroll
            for (int r = 0; r < 4; ++r)
                mt[r] = fmaxf(mt[r], __shfl_xor(mt[r], st, 64));
        float ps[4];
#pragma unroll
        for (int r = 0; r < 4; ++r) {
            float mn = fmaxf(m_[r], mt[r]);
            float f = __expf(m_[r] - mn);
            l_[r] *= f;
#pragma unroll
            for (int n = 0; n < 4; ++n) o[n][r] *= f;
            m_[r] = mn;
            ps[r] = 0.f;
        }
#pragma unroll
        for (int n = 0; n < 4; ++n)
#pragma unroll
            for (int r = 0; r < 4; ++r) {
                float p = __expf(s[n][r] - m_[r]);
                s[n][r] = p;
                ps[r] += p;
            }
#pragma unroll
        for (int st = 1; st < 16; st <<= 1)
#pragma unroll
            for (int r = 0; r < 4; ++r)
                ps[r] += __shfl_xor(ps[r], st, 64);
#pragma unroll
        for (int r = 0; r < 4; ++r) l_[r] += ps[r];

        // ---- P -> LDS (bf16), per-wave private region
#pragma unroll
        for (int n = 0; n < 4; ++n) {
            int kl = n * 16 + lo16;
#pragma unroll
            for (int r = 0; r < 4; ++r) {
                int ql = hi * 4 + r;
                u32 off = (u32)(w * 2048) + (((u32)(ql * 128 + kl * 2)) ^ ((ql & 7) << 4));
                *(u16*)((char*)Pl + off) = bf16_rne(s[n][r]);
            }
        }
        // ---- PV: O[q][d] += P[q][k] V[k][d]
        short8 pa[2];
#pragma unroll
        for (int c = 0; c < 2; ++c) {
            u32 off = (u32)(w * 2048) + (((u32)(lo16 * 128 + c * 64 + hi * 16)) ^ ((lo16 & 7) << 4));
            pa[c] = *(const short8*)((char*)Pl + off);
        }
#pragma unroll
        for (int n = 0; n < 4; ++n) {
            int dl = n * 16 + lo16;
            u32 ov0 = (u32)(dl * 128 + hi * 16) ^ ((dl & 7) << 4);
            u32 ov1 = (u32)(dl * 128 + 64 + hi * 16) ^ ((dl & 7) << 4);
            short8 vb0 = *(const short8*)((char*)Vt + ov0);
            short8 vb1 = *(const short8*)((char*)Vt + ov1);
            o[n] = MFMA16(pa[0], vb0, o[n]);
            o[n] = MFMA16(pa[1], vb1, o[n]);
        }
    }

    // ---- epilogue: O /= l, write bf16x2
#pragma unroll
    for (int r = 0; r < 4; ++r) {
        float inv = 1.0f / l_[r];
        int tokg = bb * LL + qt * 64 + w * 16 + hi * 4 + r;
#pragma unroll
        for (int n = 0; n < 4; ++n) {
            int d = n * 16 + lo16;
            float v = o[n][r] * inv;
            u16 hh = bf16_rne(v);
            size_t idx = (size_t)tokg * (NH * HD) + h * HD + d;
            avh[idx] = hh;
            avl[idx] = bf16_rne(v - bf16_to_f(hh));
        }
    }
}

// ---------------- boundary decision + blend -----------------------------
__global__ __launch_bounds__(64) void bd_kernel(
    const float* __restrict__ outb, const float* __restrict__ layer_x,
    const float* __restrict__ mm, const float* __restrict__ bd_w,
    const float* __restrict__ bd_b, float* __restrict__ d_out)
{
    int t = blockIdx.x;
    int lane = threadIdx.x;
    const float* orow = outb + (size_t)t * HID;
    float dot = 0.0f;
#pragma unroll
    for (int i = 0; i < 8; ++i) dot += orow[lane + 64 * i] * bd_w[lane + 64 * i];
    dot = wave_sum(dot);
    float mmv = mm[t];
    const float* xrow = layer_x + (size_t)t * HID;
    float* yrow = d_out + (size_t)t * HID;
#pragma unroll
    for (int i = 0; i < 8; ++i) {
        int c = lane + 64 * i;
        yrow[c] = orow[c] * mmv + (1.0f - mmv) * xrow[c];
    }
    if (lane == 0) {
        float z = dot + bd_b[0];
        d_out[(size_t)TOK * HID + t] = (z > 0.0f) ? 1.0f : 0.0f;
    }
}

extern "C" void kernel_launch(void* const* d_in, const int* in_sizes, int n_in,
                              void* d_out, int out_size, void* d_ws, size_t ws_size,
                              hipStream_t stream) {
    const float* layer_x = (const float*)d_in[0];
    const float* mm      = (const float*)d_in[2];
    const float* qkv_w   = (const float*)d_in[3];
    const float* qkv_b   = (const float*)d_in[4];
    const float* o_w     = (const float*)d_in[5];
    const float* o_b     = (const float*)d_in[6];
    const float* ln1_g   = (const float*)d_in[7];
    const float* ln1_b   = (const float*)d_in[8];
    const float* ff_w1   = (const float*)d_in[9];
    const float* ff_b1   = (const float*)d_in[10];
    const float* ff_w2   = (const float*)d_in[11];
    const float* ff_b2   = (const float*)d_in[12];
    const float* ln2_g   = (const float*)d_in[13];
    const float* ln2_b   = (const float*)d_in[14];
    const float* bd_w    = (const float*)d_in[15];
    const float* bd_b    = (const float*)d_in[16];

    char* base = (char*)d_ws;
    float* buf_out = (float*)base;                       //  8388608 B
    u16* h_hi  = (u16*)(base + 8388608);                 //  4194304
    u16* h_lo  = (u16*)(base + 12582912);                //  4194304
    u16* av_hi = (u16*)(base + 16777216);                //  4194304
    u16* av_lo = (u16*)(base + 20971520);                //  4194304
    u16* qkvb  = (u16*)(base + 25165824);                // 12582912 (aliases t)
    u16* t_hi  = (u16*)(base + 25165824);                // 16777216
    u16* t_lo  = (u16*)(base + 41943040);                // 16777216
    u16* wt_hi = (u16*)(base + 58720256);                // 12582912
    u16* wt_lo = (u16*)(base + 71303168);                // 12582912
    size_t need = 83886080;
    if (ws_size < need) return;

    const size_t WST = 3145728;  // per-layer stride in wt region (elems)
    const size_t OFF_QKV = 0, OFF_O = 786432, OFF_FF1 = 1048576, OFF_FF2 = 2097152;

    // weight prep (transpose + bf16x2 split)
    for (int l = 0; l < NLAYER; ++l) {
        size_t wb = (size_t)l * WST;
        wprep_kernel<<<dim3(QKV3 / 32, HID / 32), 256, 0, stream>>>(
            qkv_w + (size_t)l * HID * QKV3, wt_hi + wb + OFF_QKV, wt_lo + wb + OFF_QKV, HID, QKV3);
        wprep_kernel<<<dim3(HID / 32, HID / 32), 256, 0, stream>>>(
            o_w + (size_t)l * HID * HID, wt_hi + wb + OFF_O, wt_lo + wb + OFF_O, HID, HID);
        wprep_kernel<<<dim3(PROJ / 32, HID / 32), 256, 0, stream>>>(
            ff_w1 + (size_t)l * HID * PROJ, wt_hi + wb + OFF_FF1, wt_lo + wb + OFF_FF1, HID, PROJ);
        wprep_kernel<<<dim3(HID / 32, PROJ / 32), 256, 0, stream>>>(
            ff_w2 + (size_t)l * PROJ * HID, wt_hi + wb + OFF_FF2, wt_lo + wb + OFF_FF2, PROJ, HID);
    }

    hipMemcpyAsync(buf_out, layer_x, (size_t)TOK * HID * sizeof(float),
                   hipMemcpyDeviceToDevice, stream);

    for (int l = 0; l < NLAYER; ++l) {
        size_t wb = (size_t)l * WST;
        // h = LN1(out) -> bf16x2
        ln_kernel<<<TOK, 256, 0, stream>>>(buf_out, ln1_g + (size_t)l * HID,
                                           ln1_b + (size_t)l * HID, h_hi, h_lo);
        // qkv = h @ qkv_w + qkv_b  -> bf16
        gemm3<0, 1><<<dim3(QKV3 / 128, TOK / 128, 1), 256, 0, stream>>>(
            h_hi, h_lo, wt_hi + wb + OFF_QKV, wt_lo + wb + OFF_QKV,
            qkv_b + (size_t)l * QKV3, nullptr, qkvb, nullptr, TOK, QKV3, HID);
        // av = softmax(q k^T / 8) v  -> bf16x2
        attn_mfma<<<BB * NH * (LL / 64), 256, 0, stream>>>(qkvb, av_hi, av_lo);
        // out += av @ o_w + o_b   (split-K 2)
        gemm3<1, 2><<<dim3(HID / 128, TOK / 128, 2), 256, 0, stream>>>(
            av_hi, av_lo, wt_hi + wb + OFF_O, wt_lo + wb + OFF_O,
            o_b + (size_t)l * HID, buf_out, nullptr, nullptr, TOK, HID, NH * HD);
        // h = LN2(out) -> bf16x2
        ln_kernel<<<TOK, 256, 0, stream>>>(buf_out, ln2_g + (size_t)l * HID,
                                           ln2_b + (size_t)l * HID, h_hi, h_lo);
        // t = relu(h @ w1 + b1) -> bf16x2
        gemm3<2, 1><<<dim3(PROJ / 128, TOK / 128, 1), 256, 0, stream>>>(
            h_hi, h_lo, wt_hi + wb + OFF_FF1, wt_lo + wb + OFF_FF1,
            ff_b1 + (size_t)l * PROJ, nullptr, t_hi, t_lo, TOK, PROJ, HID);
        // out += t @ w2 + b2   (split-K 4)
        gemm3<1, 4><<<dim3(HID / 128, TOK / 128, 4), 256, 0, stream>>>(
            t_hi, t_lo, wt_hi + wb + OFF_FF2, wt_lo + wb + OFF_FF2,
            ff_b2 + (size_t)l * HID, buf_out, nullptr, nullptr, TOK, HID, PROJ);
    }

    bd_kernel<<<TOK, 64, 0, stream>>>(buf_out, layer_x, mm, bd_w, bd_b,
                                      (float*)d_out);
}